// Round 17
// baseline (1265.891 us; speedup 1.0000x reference)
//
#include <hip/hip_runtime.h>

// PopNet R16 (resubmit after broker timeout): kill the scratch spill. R1 showed
// VGPR_Count=64 with 128 floats of per-thread state (mem1[64]+cur1[64]) ->
// state lived in scratch (HBM!); ~192 scratch accesses/thread/step explains the
// ~350us compute-phase stall that made store optimizations null (R5=R7=R8) and
// the R14 split's 395us compute kernel. Fix: state in NAMED f32x4 registers
// (no arrays, constant component access only), macro-expanded step body,
// __launch_bounds__(256,2) (~160 VGPR < 256 budget). Store machinery identical
// to R8 (absmax 0.0 x4).

#define BINS   15
#define STEPS  25
#define NH     64
#define NO     3
#define NF     4
#define TPB    256

typedef float f32x4 __attribute__((ext_vector_type(4)));

#define LDS_BARRIER() asm volatile("s_waitcnt lgkmcnt(0)\n\ts_barrier" ::: "memory")

__global__ __launch_bounds__(TPB, 2) void popnet_kernel(
                              const float* __restrict__ x,
                              const float* __restrict__ W1,
                              const float* __restrict__ b1,
                              const float* __restrict__ W2,
                              const float* __restrict__ b2,
                              float* __restrict__ out, int B)
{
    __shared__ float W1s[NH * 60];
    __shared__ float b1s[NH];
    __shared__ float W2s[NO * NH];
    __shared__ float b2s[NO];
    __shared__ unsigned long long s1bits[2][TPB];
    __shared__ float s2f[2][TPB * NO];
    __shared__ unsigned int idxs[TPB];

    const int tid = threadIdx.x;
    for (int i = tid; i < NH * 60; i += TPB) W1s[i] = W1[i];
    for (int i = tid; i < NH;      i += TPB) b1s[i] = b1[i];
    for (int i = tid; i < NO * NH; i += TPB) W2s[i] = W2[i];
    if (tid < NO) b2s[tid] = b2[tid];
    __syncthreads();

    const int blockStart = blockIdx.x * TPB;
    const int b = blockStart + tid;

    // ---- population encode (no arrays: scalars only) ----
    const f32x4 xv = *reinterpret_cast<const f32x4*>(x + (size_t)b * NF);
    int i0, i1, i2, i3;
    {
        float v0 = fminf(fmaxf(xv.x, 0.0f), 1.0f);
        float v1 = fminf(fmaxf(xv.y, 0.0f), 1.0f);
        float v2 = fminf(fmaxf(xv.z, 0.0f), 1.0f);
        float v3 = fminf(fmaxf(xv.w, 0.0f), 1.0f);
        i0 = min(max((int)(v0 * 14.0f), 0), BINS - 1);
        i1 = min(max((int)(v1 * 14.0f), 0), BINS - 1);
        i2 = min(max((int)(v2 * 14.0f), 0), BINS - 1);
        i3 = min(max((int)(v3 * 14.0f), 0), BINS - 1);
    }
    idxs[tid] = (unsigned)i0 | ((unsigned)i1 << 4) | ((unsigned)i2 << 8) | ((unsigned)i3 << 12);
    const int c0 = i0, c1 = 15 + i1, c2 = 30 + i2, c3 = 45 + i3;

    // ---- cur1 in 16 named f32x4 (ascending adds, bias last — bit-exact lineage) ----
#define CUR1C(cq, comp, N) { const float* row_ = W1s + (N) * 60;                              \
        float s_ = __fadd_rn(__fadd_rn(__fadd_rn(row_[c0], row_[c1]), row_[c2]), row_[c3]);   \
        cq.comp = __fadd_rn(s_, b1s[N]); }
#define CUR1Q(cq, B4) CUR1C(cq, x, B4) CUR1C(cq, y, (B4)+1) CUR1C(cq, z, (B4)+2) CUR1C(cq, w, (B4)+3)

    f32x4 c00, c01, c02, c03, c04, c05, c06, c07, c08, c09, c10, c11, c12, c13, c14, c15;
    CUR1Q(c00, 0)  CUR1Q(c01, 4)  CUR1Q(c02, 8)  CUR1Q(c03, 12)
    CUR1Q(c04, 16) CUR1Q(c05, 20) CUR1Q(c06, 24) CUR1Q(c07, 28)
    CUR1Q(c08, 32) CUR1Q(c09, 36) CUR1Q(c10, 40) CUR1Q(c11, 44)
    CUR1Q(c12, 48) CUR1Q(c13, 52) CUR1Q(c14, 56) CUR1Q(c15, 60)

    f32x4 m00 = {0,0,0,0}, m01 = m00, m02 = m00, m03 = m00, m04 = m00, m05 = m00,
          m06 = m00, m07 = m00, m08 = m00, m09 = m00, m10 = m00, m11 = m00,
          m12 = m00, m13 = m00, m14 = m00, m15 = m00;
    float n2a = 0.0f, n2b = 0.0f, n2c = 0.0f;   // mem2

    const size_t off1 = (size_t)STEPS * B * NO;
    const size_t off2 = off1 + (size_t)STEPS * B * NH;
    float* const out_spk2 = out;
    float* const out_spk1 = out + off1;
    float* const out_xpop = out + off2;

    // one neuron: LIF + spike bit + 3 exact gated adds (W2s reads are wave-uniform LDS)
#define LIF1(mq, cq, comp, N) {                                                  \
        float m_ = mq.comp;                                                      \
        const float r_ = (m_ > 1.0f) ? 1.0f : 0.0f;                              \
        m_ = __fsub_rn(__fadd_rn(__fmul_rn(0.8f, m_), cq.comp), r_);             \
        mq.comp = m_;                                                            \
        const bool f_ = (m_ > 1.0f);                                             \
        bits |= ((unsigned long long)(f_ ? 1u : 0u)) << (N);                     \
        acc0 = __fadd_rn(acc0, f_ ? W2s[0 * NH + (N)] : 0.0f);                   \
        acc1 = __fadd_rn(acc1, f_ ? W2s[1 * NH + (N)] : 0.0f);                   \
        acc2 = __fadd_rn(acc2, f_ ? W2s[2 * NH + (N)] : 0.0f); }
#define LIFQ(mq, cq, B4) LIF1(mq, cq, x, B4) LIF1(mq, cq, y, (B4)+1) LIF1(mq, cq, z, (B4)+2) LIF1(mq, cq, w, (B4)+3)

    int cur = 0;
#pragma unroll 1
    for (int t = 0; t < STEPS; ++t) {
        float acc0 = 0.0f, acc1 = 0.0f, acc2 = 0.0f;
        unsigned long long bits = 0ull;
        LIFQ(m00, c00, 0)  LIFQ(m01, c01, 4)  LIFQ(m02, c02, 8)  LIFQ(m03, c03, 12)
        LIFQ(m04, c04, 16) LIFQ(m05, c05, 20) LIFQ(m06, c06, 24) LIFQ(m07, c07, 28)
        LIFQ(m08, c08, 32) LIFQ(m09, c09, 36) LIFQ(m10, c10, 40) LIFQ(m11, c11, 44)
        LIFQ(m12, c12, 48) LIFQ(m13, c13, 52) LIFQ(m14, c14, 56) LIFQ(m15, c15, 60)

        s1bits[cur][tid] = bits;

        // ---- LIF layer 2 (scalars) ----
        const float cua = __fadd_rn(acc0, b2s[0]);
        const float cub = __fadd_rn(acc1, b2s[1]);
        const float cuc = __fadd_rn(acc2, b2s[2]);
        {
            float m_ = n2a; const float r_ = (m_ > 1.0f) ? 1.0f : 0.0f;
            m_ = __fsub_rn(__fadd_rn(__fmul_rn(0.8f, m_), cua), r_);
            n2a = m_; s2f[cur][tid * NO + 0] = (m_ > 1.0f) ? 1.0f : 0.0f;
        }
        {
            float m_ = n2b; const float r_ = (m_ > 1.0f) ? 1.0f : 0.0f;
            m_ = __fsub_rn(__fadd_rn(__fmul_rn(0.8f, m_), cub), r_);
            n2b = m_; s2f[cur][tid * NO + 1] = (m_ > 1.0f) ? 1.0f : 0.0f;
        }
        {
            float m_ = n2c; const float r_ = (m_ > 1.0f) ? 1.0f : 0.0f;
            m_ = __fsub_rn(__fadd_rn(__fmul_rn(0.8f, m_), cuc), r_);
            n2c = m_; s2f[cur][tid * NO + 2] = (m_ > 1.0f) ? 1.0f : 0.0f;
        }

        LDS_BARRIER();   // LDS-only: global stores stay in flight; dbuf handles next-t reuse

        // ---- cooperative contiguous writes for this t (identical to R8) ----
        float* const base1 = out_spk1 + (size_t)t * B * NH + (size_t)blockStart * NH;
#pragma unroll
        for (int i = 0; i < 16; ++i) {
            const int f4 = tid + i * TPB;
            const unsigned long long w = s1bits[cur][f4 >> 4];
            const int nb = (f4 & 15) * 4;
            f32x4 v;
            v.x = (float)((w >> (nb + 0)) & 1ull);
            v.y = (float)((w >> (nb + 1)) & 1ull);
            v.z = (float)((w >> (nb + 2)) & 1ull);
            v.w = (float)((w >> (nb + 3)) & 1ull);
            reinterpret_cast<f32x4*>(base1)[f4] = v;
        }
        float* const base2 = out_spk2 + (size_t)t * B * NO + (size_t)blockStart * NO;
        if (tid < (TPB * NO) / 4) {
            f32x4 v;
            v.x = s2f[cur][tid * 4 + 0];
            v.y = s2f[cur][tid * 4 + 1];
            v.z = s2f[cur][tid * 4 + 2];
            v.w = s2f[cur][tid * 4 + 3];
            reinterpret_cast<f32x4*>(base2)[tid] = v;
        }
        cur ^= 1;
    }

    // ---- x_pop one-hot (identical to R8) ----
    float* const basex = out_xpop + (size_t)blockStart * 60;
#pragma unroll
    for (int i = 0; i < 15; ++i) {
        const int g = tid + i * TPB;
        const int bb = g / 15;
        const int r = g - bb * 15;
        const unsigned pk = idxs[bb];
        const int j0 = r * 4;
        f32x4 v;
#pragma unroll
        for (int k = 0; k < 4; ++k) {
            const int j = j0 + k;
            const int feat = j / 15;
            const int bin = j - feat * 15;
            v[k] = (bin == (int)((pk >> (feat * 4)) & 15u)) ? 1.0f : 0.0f;
        }
        reinterpret_cast<f32x4*>(basex)[g] = v;
    }
}

extern "C" void kernel_launch(void* const* d_in, const int* in_sizes, int n_in,
                              void* d_out, int out_size, void* d_ws, size_t ws_size,
                              hipStream_t stream) {
    const float* x  = (const float*)d_in[0];
    const float* W1 = (const float*)d_in[1];
    const float* b1 = (const float*)d_in[2];
    const float* W2 = (const float*)d_in[3];
    const float* b2 = (const float*)d_in[4];
    float* out = (float*)d_out;
    const int B = in_sizes[0] / NF;
    popnet_kernel<<<B / TPB, TPB, 0, stream>>>(x, W1, b1, W2, b2, out, B);
}